// Round 1
// baseline (450.107 us; speedup 1.0000x reference)
//
#include <hip/hip_runtime.h>

// ---------------------------------------------------------------------------
// LinearAttention: out = (featmap(xWq+bq) @ [K^T V]) / (q . sum K + eps) @ Wo + bo
// featmap(t) = elu(t)+1 = t>0 ? t+1 : exp(t)
// B=4, S=4096, D_MODEL=1024, H=16, DK=64. All inputs fp32; compute in bf16 MFMA.
// ---------------------------------------------------------------------------

typedef __bf16 bf16;
typedef float  f32x4  __attribute__((ext_vector_type(4)));
typedef short  s16x8  __attribute__((ext_vector_type(8)));   // 8 bf16 = 4 VGPRs (MFMA A/B frag)
typedef bf16   bf16x4 __attribute__((ext_vector_type(4)));

#define BATCH 4
#define SEQ   4096
#define DM    1024
#define NH    16
#define DK    64
#define MROWS (BATCH*SEQ)            // 16384
#define EPSV  1e-6f

// ---------------------------------------------------------------- conv_x ----
__global__ __launch_bounds__(256) void conv_x_kernel(const float* __restrict__ x,
                                                     bf16* __restrict__ xb) {
  int i = (blockIdx.x * 256 + threadIdx.x) * 4;
  float4 f = *reinterpret_cast<const float4*>(x + i);
  bf16x4 o;
  o[0] = (bf16)f.x; o[1] = (bf16)f.y; o[2] = (bf16)f.z; o[3] = (bf16)f.w;
  *reinterpret_cast<bf16x4*>(xb + i) = o;
}

// ------------------------------------------------------- conv_w (transpose) -
// Wt[z*1024 + n][k] = Wz[k][n]  (bf16), z in {q,k,v,o}
__global__ __launch_bounds__(256) void conv_w_kernel(const float* __restrict__ W0,
                                                     const float* __restrict__ W1,
                                                     const float* __restrict__ W2,
                                                     const float* __restrict__ W3,
                                                     bf16* __restrict__ Wt) {
  __shared__ float t[32][33];
  const int z = blockIdx.z;
  const float* W = (z == 0) ? W0 : (z == 1) ? W1 : (z == 2) ? W2 : W3;
  const int n0 = blockIdx.x * 32, k0 = blockIdx.y * 32;
  const int tx = threadIdx.x, ty = threadIdx.y;       // (32,8)
#pragma unroll
  for (int i = 0; i < 4; ++i)
    t[ty + i * 8][tx] = W[(size_t)(k0 + ty + i * 8) * DM + n0 + tx];
  __syncthreads();
#pragma unroll
  for (int i = 0; i < 4; ++i)
    Wt[(size_t)(z * DM + n0 + ty + i * 8) * DM + k0 + tx] = (bf16)t[tx][ty + i * 8];
}

// ------------------------------------------------------------------ GEMM ----
// C[M,N] = A[M,K] * Bt[N,K]^T, K=1024, 128x128 block tile, 4 waves of 64x64,
// 16x16x32 bf16 MFMA. MODE 0: bias + featmap(q,k parts) -> bf16 QKV (ldc=3072).
// MODE 1: + bias -> fp32 out (ldc=1024).
template <int MODE>
__global__ __launch_bounds__(256) void gemm_bf16(const bf16* __restrict__ A,
                                                 const bf16* __restrict__ Bt,
                                                 void* __restrict__ Cout, int ldc,
                                                 const float* __restrict__ b0,
                                                 const float* __restrict__ b1,
                                                 const float* __restrict__ b2) {
  constexpr int K = 1024;
  __shared__ bf16 As[128][32];
  __shared__ bf16 Bs[128][32];
  const int tid  = threadIdx.x;
  const int wave = tid >> 6, lane = tid & 63;
  const int quad = lane >> 4, l16 = lane & 15;
  const int bm0 = blockIdx.y * 128, bn0 = blockIdx.x * 128;
  const int wm = (wave >> 1) * 64, wn = (wave & 1) * 64;

  f32x4 acc[4][4] = {};

  // staging: 512 chunks of 8 bf16 per tile; 2 chunks/thread; 4 chunks per row of 32
  const int r0 = tid >> 2,          o0 = (tid & 3) * 8;
  const int r1 = (tid + 256) >> 2,  o1 = ((tid + 256) & 3) * 8;
  const bf16* Ap = A  + (size_t)bm0 * K;
  const bf16* Bp = Bt + (size_t)bn0 * K;

  for (int k0 = 0; k0 < K; k0 += 32) {
    *reinterpret_cast<uint4*>(&As[r0][o0]) =
        *reinterpret_cast<const uint4*>(Ap + (size_t)r0 * K + k0 + o0);
    *reinterpret_cast<uint4*>(&As[r1][o1]) =
        *reinterpret_cast<const uint4*>(Ap + (size_t)r1 * K + k0 + o1);
    *reinterpret_cast<uint4*>(&Bs[r0][o0]) =
        *reinterpret_cast<const uint4*>(Bp + (size_t)r0 * K + k0 + o0);
    *reinterpret_cast<uint4*>(&Bs[r1][o1]) =
        *reinterpret_cast<const uint4*>(Bp + (size_t)r1 * K + k0 + o1);
    __syncthreads();
    s16x8 af[4], bfr[4];
#pragma unroll
    for (int mi = 0; mi < 4; ++mi)
      af[mi] = *reinterpret_cast<const s16x8*>(&As[wm + mi * 16 + l16][quad * 8]);
#pragma unroll
    for (int ni = 0; ni < 4; ++ni)
      bfr[ni] = *reinterpret_cast<const s16x8*>(&Bs[wn + ni * 16 + l16][quad * 8]);
#pragma unroll
    for (int mi = 0; mi < 4; ++mi)
#pragma unroll
      for (int ni = 0; ni < 4; ++ni)
        acc[mi][ni] = __builtin_amdgcn_mfma_f32_16x16x32_bf16(af[mi], bfr[ni],
                                                              acc[mi][ni], 0, 0, 0);
    __syncthreads();
  }

  // epilogue: D layout col = lane&15, row = quad*4 + reg (m89/m91-verified)
  if (MODE == 0) {
    const int part = bn0 >> 10;  // 0=q 1=k 2=v (block never straddles: 128 | 1024)
    const float* bp = (part == 0) ? b0 : (part == 1) ? b1 : b2;
    bf16* C = (bf16*)Cout;
#pragma unroll
    for (int ni = 0; ni < 4; ++ni) {
      const int n_g = bn0 + wn + ni * 16 + l16;
      const float bias = bp[n_g & 1023];
#pragma unroll
      for (int mi = 0; mi < 4; ++mi) {
#pragma unroll
        for (int reg = 0; reg < 4; ++reg) {
          const int m_g = bm0 + wm + mi * 16 + quad * 4 + reg;
          float v = acc[mi][ni][reg] + bias;
          if (part < 2) v = (v > 0.f) ? (v + 1.f) : __expf(v);  // elu+1
          C[(size_t)m_g * ldc + n_g] = (bf16)v;
        }
      }
    }
  } else {
    float* C = (float*)Cout;
#pragma unroll
    for (int ni = 0; ni < 4; ++ni) {
      const int n_g = bn0 + wn + ni * 16 + l16;
      const float bias = b0[n_g];
#pragma unroll
      for (int mi = 0; mi < 4; ++mi) {
#pragma unroll
        for (int reg = 0; reg < 4; ++reg) {
          const int m_g = bm0 + wm + mi * 16 + quad * 4 + reg;
          C[(size_t)m_g * ldc + n_g] = acc[mi][ni][reg] + bias;
        }
      }
    }
  }
}

// --------------------------------------------------------------- kv_ksum ----
// kv[bh][d][e] += sum_s K[s,d]*V[s,e];  ksum[bh][d] += sum_s K[s,d]
// grid (16 s-chunks of 256, 64 bh) ; 256 thr ; thread owns 4x4 (d,e) block
__global__ __launch_bounds__(256) void kv_ksum_kernel(const bf16* __restrict__ QKV,
                                                      float* __restrict__ kv,
                                                      float* __restrict__ ksum) {
  __shared__ bf16 Ks[128][64];
  __shared__ bf16 Vs[128][64];
  const int bh = blockIdx.y;
  const int b = bh >> 4, h = bh & 15;
  const int tid = threadIdx.x;
  const int d0 = (tid >> 4) * 4, e0 = (tid & 15) * 4;
  const size_t base = (size_t)b * SEQ * 3072;
  const int colK = 1024 + h * 64, colV = 2048 + h * 64;

  float acc[4][4] = {};
  float ks = 0.f;

  for (int cc = 0; cc < 2; ++cc) {
    const int s0 = blockIdx.x * 256 + cc * 128;
#pragma unroll
    for (int i = 0; i < 4; ++i) {           // 1024 chunks of 8 bf16 per tile
      const int c = tid + i * 256;
      const int row = c >> 3, off = (c & 7) * 8;
      const size_t roff = base + (size_t)(s0 + row) * 3072;
      *reinterpret_cast<uint4*>(&Ks[row][off]) =
          *reinterpret_cast<const uint4*>(QKV + roff + colK + off);
      *reinterpret_cast<uint4*>(&Vs[row][off]) =
          *reinterpret_cast<const uint4*>(QKV + roff + colV + off);
    }
    __syncthreads();
#pragma unroll 4
    for (int s = 0; s < 128; ++s) {
      bf16x4 kk = *reinterpret_cast<const bf16x4*>(&Ks[s][d0]);
      bf16x4 vv = *reinterpret_cast<const bf16x4*>(&Vs[s][e0]);
      float kd[4], ve[4];
#pragma unroll
      for (int j = 0; j < 4; ++j) { kd[j] = (float)kk[j]; ve[j] = (float)vv[j]; }
#pragma unroll
      for (int i = 0; i < 4; ++i)
#pragma unroll
        for (int j = 0; j < 4; ++j) acc[i][j] += kd[i] * ve[j];
    }
    if (tid < 64) {
#pragma unroll 8
      for (int s = 0; s < 128; ++s) ks += (float)Ks[s][tid];
    }
    __syncthreads();
  }
#pragma unroll
  for (int i = 0; i < 4; ++i)
#pragma unroll
    for (int j = 0; j < 4; ++j)
      atomicAdd(&kv[(size_t)bh * 4096 + (d0 + i) * 64 + e0 + j], acc[i][j]);
  if (tid < 64) atomicAdd(&ksum[bh * 64 + tid], ks);
}

// ------------------------------------------------------------------ attn ----
// ATT[b,s, h*64+e] = (sum_d q[s,d]*kv[d,e]) / (q[s,:].ksum + eps)   (bf16 out)
// grid (32 s-tiles of 128, 64 bh)
__global__ __launch_bounds__(256) void attn_kernel(const bf16* __restrict__ QKV,
                                                   const float* __restrict__ kv,
                                                   const float* __restrict__ ksum,
                                                   bf16* __restrict__ ATT) {
  __shared__ bf16 qs[128][72];       // pad 64->72 to spread z-pass banks
  __shared__ float kvs[64][64];
  __shared__ float zr[128];
  __shared__ float kss[64];
  const int bh = blockIdx.y;
  const int b = bh >> 4, h = bh & 15;
  const int s0 = blockIdx.x * 128;
  const int tid = threadIdx.x, wave = tid >> 6, lane = tid & 63;
  const size_t base = (size_t)b * SEQ * 3072;
  const int colQ = h * 64;

#pragma unroll
  for (int i = 0; i < 4; ++i) {      // stage q tile 128x64
    const int c = tid + i * 256;
    const int row = c >> 3, off = (c & 7) * 8;
    *reinterpret_cast<uint4*>(&qs[row][off]) =
        *reinterpret_cast<const uint4*>(QKV + base + (size_t)(s0 + row) * 3072 + colQ + off);
  }
  const float* kvg = kv + (size_t)bh * 4096;
#pragma unroll
  for (int i = 0; i < 4; ++i) {      // stage kv 64x64 fp32
    const int c = tid + i * 256;
    const int row = c >> 4, off = (c & 15) * 4;
    *reinterpret_cast<float4*>(&kvs[row][off]) =
        *reinterpret_cast<const float4*>(kvg + row * 64 + off);
  }
  if (tid < 64) kss[tid] = ksum[bh * 64 + tid];
  __syncthreads();

  if (tid < 128) {                   // 1/(z+eps) per row
    float z = 0.f;
#pragma unroll
    for (int d = 0; d < 64; d += 4) {
      bf16x4 q4 = *reinterpret_cast<const bf16x4*>(&qs[tid][d]);
      z += (float)q4[0] * kss[d] + (float)q4[1] * kss[d + 1] +
           (float)q4[2] * kss[d + 2] + (float)q4[3] * kss[d + 3];
    }
    zr[tid] = 1.0f / (z + EPSV);
  }
  __syncthreads();

  const int e0 = (lane & 15) * 4;
  for (int it = 0; it < 2; ++it) {
    const int rb = it * 64 + wave * 16 + (lane >> 4) * 4;
    float acc[4][4] = {};
    for (int d = 0; d < 64; ++d) {
      const float4 kvv = *reinterpret_cast<const float4*>(&kvs[d][e0]);
#pragma unroll
      for (int rr = 0; rr < 4; ++rr) {
        const float qv = (float)qs[rb + rr][d];
        acc[rr][0] += qv * kvv.x; acc[rr][1] += qv * kvv.y;
        acc[rr][2] += qv * kvv.z; acc[rr][3] += qv * kvv.w;
      }
    }
#pragma unroll
    for (int rr = 0; rr < 4; ++rr) {
      const float zi = zr[rb + rr];
      bf16x4 o;
      o[0] = (bf16)(acc[rr][0] * zi); o[1] = (bf16)(acc[rr][1] * zi);
      o[2] = (bf16)(acc[rr][2] * zi); o[3] = (bf16)(acc[rr][3] * zi);
      *reinterpret_cast<bf16x4*>(ATT + ((size_t)b * SEQ + s0 + rb + rr) * DM + h * 64 + e0) = o;
    }
  }
}

// ---------------------------------------------------------------- launch ----
extern "C" void kernel_launch(void* const* d_in, const int* in_sizes, int n_in,
                              void* d_out, int out_size, void* d_ws, size_t ws_size,
                              hipStream_t stream) {
  const float* x  = (const float*)d_in[0];
  const float* Wq = (const float*)d_in[1];
  const float* bq = (const float*)d_in[2];
  const float* Wk = (const float*)d_in[3];
  const float* bk = (const float*)d_in[4];
  const float* Wv = (const float*)d_in[5];
  const float* bv = (const float*)d_in[6];
  const float* Wo = (const float*)d_in[7];
  const float* bo = (const float*)d_in[8];
  float* out = (float*)d_out;

  char* ws = (char*)d_ws;
  bf16*  Xb   = (bf16*)ws;   ws += (size_t)MROWS * DM * 2;        // 32 MB
  bf16*  Wt   = (bf16*)ws;   ws += (size_t)4 * DM * DM * 2;       // 8 MB (qkv^T + o^T)
  bf16*  QKV  = (bf16*)ws;   ws += (size_t)MROWS * 3 * DM * 2;    // 96 MB
  bf16*  ATT  = (bf16*)ws;   ws += (size_t)MROWS * DM * 2;        // 32 MB
  float* kvp  = (float*)ws;  ws += (size_t)64 * 4096 * 4;         // 1 MB
  float* ksum = (float*)ws;  ws += (size_t)64 * 64 * 4;           // 16 KB

  (void)hipMemsetAsync(kvp, 0, (size_t)64 * 4096 * 4 + (size_t)64 * 64 * 4, stream);

  conv_x_kernel<<<MROWS * DM / 1024, 256, 0, stream>>>(x, Xb);
  conv_w_kernel<<<dim3(32, 32, 4), dim3(32, 8), 0, stream>>>(Wq, Wk, Wv, Wo, Wt);
  gemm_bf16<0><<<dim3(24, 128), 256, 0, stream>>>(Xb, Wt, QKV, 3 * DM, bq, bk, bv);
  kv_ksum_kernel<<<dim3(16, 64), 256, 0, stream>>>(QKV, kvp, ksum);
  attn_kernel<<<dim3(32, 64), 256, 0, stream>>>(QKV, kvp, ksum, ATT);
  gemm_bf16<1><<<dim3(8, 128), 256, 0, stream>>>(ATT, Wt + (size_t)3 * DM * DM, out, DM, bo, bo, bo);
}

// Round 2
// 448.306 us; speedup vs baseline: 1.0040x; 1.0040x over previous
//
#include <hip/hip_runtime.h>

// ---------------------------------------------------------------------------
// LinearAttention: out = (featmap(xWq+bq) @ [K^T V]) / (q . sum K + eps) @ Wo + bo
// featmap(t) = elu(t)+1 = t>0 ? t+1 : exp(t)
// B=4, S=4096, D_MODEL=1024, H=16, DK=64. All inputs fp32; compute in bf16 MFMA.
// R2: GEMM staging via __builtin_amdgcn_global_load_lds width-16 (m97 ladder).
// ---------------------------------------------------------------------------

typedef __bf16 bf16;
typedef float  f32x4  __attribute__((ext_vector_type(4)));
typedef short  s16x8  __attribute__((ext_vector_type(8)));   // 8 bf16 = 4 VGPRs (MFMA A/B frag)
typedef bf16   bf16x4 __attribute__((ext_vector_type(4)));

#define BATCH 4
#define SEQ   4096
#define DM    1024
#define NH    16
#define DK    64
#define MROWS (BATCH*SEQ)            // 16384
#define EPSV  1e-6f

// async 16B global->LDS (DMA, no VGPR round trip). LDS dest must be
// wave-uniform base; HW writes base + lane*16.
__device__ __forceinline__ void async_cp16(const bf16* g, bf16* l) {
  __builtin_amdgcn_global_load_lds((const __attribute__((address_space(1))) void*)g,
                                   (__attribute__((address_space(3))) void*)l,
                                   16, 0, 0);
}

// ---------------------------------------------------------------- conv_x ----
__global__ __launch_bounds__(256) void conv_x_kernel(const float* __restrict__ x,
                                                     bf16* __restrict__ xb) {
  int i = (blockIdx.x * 256 + threadIdx.x) * 4;
  float4 f = *reinterpret_cast<const float4*>(x + i);
  bf16x4 o;
  o[0] = (bf16)f.x; o[1] = (bf16)f.y; o[2] = (bf16)f.z; o[3] = (bf16)f.w;
  *reinterpret_cast<bf16x4*>(xb + i) = o;
}

// ------------------------------------------------------- conv_w (transpose) -
// Wt[z*1024 + n][k] = Wz[k][n]  (bf16), z in {q,k,v,o}
__global__ __launch_bounds__(256) void conv_w_kernel(const float* __restrict__ W0,
                                                     const float* __restrict__ W1,
                                                     const float* __restrict__ W2,
                                                     const float* __restrict__ W3,
                                                     bf16* __restrict__ Wt) {
  __shared__ float t[32][33];
  const int z = blockIdx.z;
  const float* W = (z == 0) ? W0 : (z == 1) ? W1 : (z == 2) ? W2 : W3;
  const int n0 = blockIdx.x * 32, k0 = blockIdx.y * 32;
  const int tx = threadIdx.x, ty = threadIdx.y;       // (32,8)
#pragma unroll
  for (int i = 0; i < 4; ++i)
    t[ty + i * 8][tx] = W[(size_t)(k0 + ty + i * 8) * DM + n0 + tx];
  __syncthreads();
#pragma unroll
  for (int i = 0; i < 4; ++i)
    Wt[(size_t)(z * DM + n0 + ty + i * 8) * DM + k0 + tx] = (bf16)t[tx][ty + i * 8];
}

// ------------------------------------------------------------------ GEMM ----
// C[M,N] = A[M,K] * Bt[N,K]^T, K=1024, 128x128 block tile, 4 waves of 64x64,
// 16x16x32 bf16 MFMA, global_load_lds dwordx4 staging.
// MODE 0: bias + featmap(q,k parts) -> bf16 QKV (ldc=3072).
// MODE 1: + bias -> fp32 out (ldc=1024).
template <int MODE>
__global__ __launch_bounds__(256) void gemm_bf16(const bf16* __restrict__ A,
                                                 const bf16* __restrict__ Bt,
                                                 void* __restrict__ Cout, int ldc,
                                                 const float* __restrict__ b0,
                                                 const float* __restrict__ b1,
                                                 const float* __restrict__ b2) {
  constexpr int K = 1024;
  __shared__ bf16 As[128][32];
  __shared__ bf16 Bs[128][32];
  const int tid  = threadIdx.x;
  const int wave = tid >> 6, lane = tid & 63;
  const int quad = lane >> 4, l16 = lane & 15;
  const int bm0 = blockIdx.y * 128, bn0 = blockIdx.x * 128;
  const int wm = (wave >> 1) * 64, wn = (wave & 1) * 64;

  f32x4 acc[4][4] = {};

  // staging: wave w covers tile rows [w*32, w*32+32) in two 16-row DMA issues;
  // lane i -> row base + i/4, col bytes (i&3)*16  == LDS base + i*16.
  const int srow = wave * 32 + (lane >> 2);
  const int scol = (lane & 3) * 8;                       // elements
  const bf16* Ag = A  + (size_t)(bm0 + srow) * K + scol;
  const bf16* Bg = Bt + (size_t)(bn0 + srow) * K + scol;
  bf16* As0 = &As[wave * 32][0];
  bf16* As1 = &As[wave * 32 + 16][0];
  bf16* Bs0 = &Bs[wave * 32][0];
  bf16* Bs1 = &Bs[wave * 32 + 16][0];

  for (int k0 = 0; k0 < K; k0 += 32) {
    async_cp16(Ag,          As0);
    async_cp16(Ag + 16 * K, As1);
    async_cp16(Bg,          Bs0);
    async_cp16(Bg + 16 * K, Bs1);
    Ag += 32; Bg += 32;
    __syncthreads();                      // drains vmcnt(0) before barrier
    s16x8 af[4], bfr[4];
#pragma unroll
    for (int mi = 0; mi < 4; ++mi)
      af[mi] = *reinterpret_cast<const s16x8*>(&As[wm + mi * 16 + l16][quad * 8]);
#pragma unroll
    for (int ni = 0; ni < 4; ++ni)
      bfr[ni] = *reinterpret_cast<const s16x8*>(&Bs[wn + ni * 16 + l16][quad * 8]);
#pragma unroll
    for (int mi = 0; mi < 4; ++mi)
#pragma unroll
      for (int ni = 0; ni < 4; ++ni)
        acc[mi][ni] = __builtin_amdgcn_mfma_f32_16x16x32_bf16(af[mi], bfr[ni],
                                                              acc[mi][ni], 0, 0, 0);
    __syncthreads();
  }

  // epilogue: D layout col = lane&15, row = quad*4 + reg (m89/m91-verified)
  if (MODE == 0) {
    const int part = bn0 >> 10;  // 0=q 1=k 2=v (block never straddles: 128 | 1024)
    const float* bp = (part == 0) ? b0 : (part == 1) ? b1 : b2;
    bf16* C = (bf16*)Cout;
#pragma unroll
    for (int ni = 0; ni < 4; ++ni) {
      const int n_g = bn0 + wn + ni * 16 + l16;
      const float bias = bp[n_g & 1023];
#pragma unroll
      for (int mi = 0; mi < 4; ++mi) {
#pragma unroll
        for (int reg = 0; reg < 4; ++reg) {
          const int m_g = bm0 + wm + mi * 16 + quad * 4 + reg;
          float v = acc[mi][ni][reg] + bias;
          if (part < 2) v = (v > 0.f) ? (v + 1.f) : __expf(v);  // elu+1
          C[(size_t)m_g * ldc + n_g] = (bf16)v;
        }
      }
    }
  } else {
    float* C = (float*)Cout;
#pragma unroll
    for (int ni = 0; ni < 4; ++ni) {
      const int n_g = bn0 + wn + ni * 16 + l16;
      const float bias = b0[n_g];
#pragma unroll
      for (int mi = 0; mi < 4; ++mi) {
#pragma unroll
        for (int reg = 0; reg < 4; ++reg) {
          const int m_g = bm0 + wm + mi * 16 + quad * 4 + reg;
          C[(size_t)m_g * ldc + n_g] = acc[mi][ni][reg] + bias;
        }
      }
    }
  }
}

// --------------------------------------------------------------- kv_ksum ----
// kv[bh][d][e] += sum_s K[s,d]*V[s,e];  ksum[bh][d] += sum_s K[s,d]
// grid (16 s-chunks of 256, 64 bh) ; 256 thr ; thread owns 4x4 (d,e) block
__global__ __launch_bounds__(256) void kv_ksum_kernel(const bf16* __restrict__ QKV,
                                                      float* __restrict__ kv,
                                                      float* __restrict__ ksum) {
  __shared__ bf16 Ks[128][64];
  __shared__ bf16 Vs[128][64];
  const int bh = blockIdx.y;
  const int b = bh >> 4, h = bh & 15;
  const int tid = threadIdx.x;
  const int d0 = (tid >> 4) * 4, e0 = (tid & 15) * 4;
  const size_t base = (size_t)b * SEQ * 3072;
  const int colK = 1024 + h * 64, colV = 2048 + h * 64;

  float acc[4][4] = {};
  float ks = 0.f;

  for (int cc = 0; cc < 2; ++cc) {
    const int s0 = blockIdx.x * 256 + cc * 128;
#pragma unroll
    for (int i = 0; i < 4; ++i) {           // 1024 chunks of 8 bf16 per tile
      const int c = tid + i * 256;
      const int row = c >> 3, off = (c & 7) * 8;
      const size_t roff = base + (size_t)(s0 + row) * 3072;
      *reinterpret_cast<uint4*>(&Ks[row][off]) =
          *reinterpret_cast<const uint4*>(QKV + roff + colK + off);
      *reinterpret_cast<uint4*>(&Vs[row][off]) =
          *reinterpret_cast<const uint4*>(QKV + roff + colV + off);
    }
    __syncthreads();
#pragma unroll 4
    for (int s = 0; s < 128; ++s) {
      bf16x4 kk = *reinterpret_cast<const bf16x4*>(&Ks[s][d0]);
      bf16x4 vv = *reinterpret_cast<const bf16x4*>(&Vs[s][e0]);
      float kd[4], ve[4];
#pragma unroll
      for (int j = 0; j < 4; ++j) { kd[j] = (float)kk[j]; ve[j] = (float)vv[j]; }
#pragma unroll
      for (int i = 0; i < 4; ++i)
#pragma unroll
        for (int j = 0; j < 4; ++j) acc[i][j] += kd[i] * ve[j];
    }
    if (tid < 64) {
#pragma unroll 8
      for (int s = 0; s < 128; ++s) ks += (float)Ks[s][tid];
    }
    __syncthreads();
  }
#pragma unroll
  for (int i = 0; i < 4; ++i)
#pragma unroll
    for (int j = 0; j < 4; ++j)
      atomicAdd(&kv[(size_t)bh * 4096 + (d0 + i) * 64 + e0 + j], acc[i][j]);
  if (tid < 64) atomicAdd(&ksum[bh * 64 + tid], ks);
}

// ------------------------------------------------------------------ attn ----
// ATT[b,s, h*64+e] = (sum_d q[s,d]*kv[d,e]) / (q[s,:].ksum + eps)   (bf16 out)
// grid (32 s-tiles of 128, 64 bh)
__global__ __launch_bounds__(256) void attn_kernel(const bf16* __restrict__ QKV,
                                                   const float* __restrict__ kv,
                                                   const float* __restrict__ ksum,
                                                   bf16* __restrict__ ATT) {
  __shared__ bf16 qs[128][72];       // pad 64->72 to spread z-pass banks
  __shared__ float kvs[64][64];
  __shared__ float zr[128];
  __shared__ float kss[64];
  const int bh = blockIdx.y;
  const int b = bh >> 4, h = bh & 15;
  const int s0 = blockIdx.x * 128;
  const int tid = threadIdx.x, wave = tid >> 6, lane = tid & 63;
  const size_t base = (size_t)b * SEQ * 3072;
  const int colQ = h * 64;

#pragma unroll
  for (int i = 0; i < 4; ++i) {      // stage q tile 128x64
    const int c = tid + i * 256;
    const int row = c >> 3, off = (c & 7) * 8;
    *reinterpret_cast<uint4*>(&qs[row][off]) =
        *reinterpret_cast<const uint4*>(QKV + base + (size_t)(s0 + row) * 3072 + colQ + off);
  }
  const float* kvg = kv + (size_t)bh * 4096;
#pragma unroll
  for (int i = 0; i < 4; ++i) {      // stage kv 64x64 fp32
    const int c = tid + i * 256;
    const int row = c >> 4, off = (c & 15) * 4;
    *reinterpret_cast<float4*>(&kvs[row][off]) =
        *reinterpret_cast<const float4*>(kvg + row * 64 + off);
  }
  if (tid < 64) kss[tid] = ksum[bh * 64 + tid];
  __syncthreads();

  if (tid < 128) {                   // 1/(z+eps) per row
    float z = 0.f;
#pragma unroll
    for (int d = 0; d < 64; d += 4) {
      bf16x4 q4 = *reinterpret_cast<const bf16x4*>(&qs[tid][d]);
      z += (float)q4[0] * kss[d] + (float)q4[1] * kss[d + 1] +
           (float)q4[2] * kss[d + 2] + (float)q4[3] * kss[d + 3];
    }
    zr[tid] = 1.0f / (z + EPSV);
  }
  __syncthreads();

  const int e0 = (lane & 15) * 4;
  for (int it = 0; it < 2; ++it) {
    const int rb = it * 64 + wave * 16 + (lane >> 4) * 4;
    float acc[4][4] = {};
    for (int d = 0; d < 64; ++d) {
      const float4 kvv = *reinterpret_cast<const float4*>(&kvs[d][e0]);
#pragma unroll
      for (int rr = 0; rr < 4; ++rr) {
        const float qv = (float)qs[rb + rr][d];
        acc[rr][0] += qv * kvv.x; acc[rr][1] += qv * kvv.y;
        acc[rr][2] += qv * kvv.z; acc[rr][3] += qv * kvv.w;
      }
    }
#pragma unroll
    for (int rr = 0; rr < 4; ++rr) {
      const float zi = zr[rb + rr];
      bf16x4 o;
      o[0] = (bf16)(acc[rr][0] * zi); o[1] = (bf16)(acc[rr][1] * zi);
      o[2] = (bf16)(acc[rr][2] * zi); o[3] = (bf16)(acc[rr][3] * zi);
      *reinterpret_cast<bf16x4*>(ATT + ((size_t)b * SEQ + s0 + rb + rr) * DM + h * 64 + e0) = o;
    }
  }
}

// ---------------------------------------------------------------- launch ----
extern "C" void kernel_launch(void* const* d_in, const int* in_sizes, int n_in,
                              void* d_out, int out_size, void* d_ws, size_t ws_size,
                              hipStream_t stream) {
  const float* x  = (const float*)d_in[0];
  const float* Wq = (const float*)d_in[1];
  const float* bq = (const float*)d_in[2];
  const float* Wk = (const float*)d_in[3];
  const float* bk = (const float*)d_in[4];
  const float* Wv = (const float*)d_in[5];
  const float* bv = (const float*)d_in[6];
  const float* Wo = (const float*)d_in[7];
  const float* bo = (const float*)d_in[8];
  float* out = (float*)d_out;

  char* ws = (char*)d_ws;
  bf16*  Xb   = (bf16*)ws;   ws += (size_t)MROWS * DM * 2;        // 32 MB
  bf16*  Wt   = (bf16*)ws;   ws += (size_t)4 * DM * DM * 2;       // 8 MB (qkv^T + o^T)
  bf16*  QKV  = (bf16*)ws;   ws += (size_t)MROWS * 3 * DM * 2;    // 96 MB
  bf16*  ATT  = (bf16*)ws;   ws += (size_t)MROWS * DM * 2;        // 32 MB
  float* kvp  = (float*)ws;  ws += (size_t)64 * 4096 * 4;         // 1 MB
  float* ksum = (float*)ws;  ws += (size_t)64 * 64 * 4;           // 16 KB

  (void)hipMemsetAsync(kvp, 0, (size_t)64 * 4096 * 4 + (size_t)64 * 64 * 4, stream);

  conv_x_kernel<<<MROWS * DM / 1024, 256, 0, stream>>>(x, Xb);
  conv_w_kernel<<<dim3(32, 32, 4), dim3(32, 8), 0, stream>>>(Wq, Wk, Wv, Wo, Wt);
  gemm_bf16<0><<<dim3(24, 128), 256, 0, stream>>>(Xb, Wt, QKV, 3 * DM, bq, bk, bv);
  kv_ksum_kernel<<<dim3(16, 64), 256, 0, stream>>>(QKV, kvp, ksum);
  attn_kernel<<<dim3(32, 64), 256, 0, stream>>>(QKV, kvp, ksum, ATT);
  gemm_bf16<1><<<dim3(8, 128), 256, 0, stream>>>(ATT, Wt + (size_t)3 * DM * DM, out, DM, bo, bo, bo);
}

// Round 3
// 444.524 us; speedup vs baseline: 1.0126x; 1.0085x over previous
//
#include <hip/hip_runtime.h>

// ---------------------------------------------------------------------------
// LinearAttention: out = (featmap(xWq+bq) @ [K^T V]) / (q . sum K + eps) @ Wo + bo
// featmap(t) = elu(t)+1 = t>0 ? t+1 : exp(t)
// B=4, S=4096, D_MODEL=1024, H=16, DK=64. Inputs fp32; compute in bf16 MFMA.
// R3: BK=64, XOR bank swizzle on LDS tiles (kills 8-way read conflicts),
//     LDS-staged coalesced epilogue (kills partial-line write RMW).
// ---------------------------------------------------------------------------

typedef __bf16 bf16;
typedef float  f32x4  __attribute__((ext_vector_type(4)));
typedef short  s16x8  __attribute__((ext_vector_type(8)));   // 8 bf16 = 4 VGPRs (MFMA A/B frag)
typedef bf16   bf16x4 __attribute__((ext_vector_type(4)));

#define BATCH 4
#define SEQ   4096
#define DM    1024
#define NH    16
#define DK    64
#define MROWS (BATCH*SEQ)            // 16384
#define EPSV  1e-6f

// async 16B global->LDS DMA. LDS dest is wave-uniform base; HW writes
// base + lane*16.
__device__ __forceinline__ void async_cp16(const bf16* g, bf16* l) {
  __builtin_amdgcn_global_load_lds((const __attribute__((address_space(1))) void*)g,
                                   (__attribute__((address_space(3))) void*)l,
                                   16, 0, 0);
}

// ---------------------------------------------------------------- conv_x ----
__global__ __launch_bounds__(256) void conv_x_kernel(const float* __restrict__ x,
                                                     bf16* __restrict__ xb) {
  int i = (blockIdx.x * 256 + threadIdx.x) * 4;
  float4 f = *reinterpret_cast<const float4*>(x + i);
  bf16x4 o;
  o[0] = (bf16)f.x; o[1] = (bf16)f.y; o[2] = (bf16)f.z; o[3] = (bf16)f.w;
  *reinterpret_cast<bf16x4*>(xb + i) = o;
}

// ------------------------------------------------------- conv_w (transpose) -
// Wt[z*1024 + n][k] = Wz[k][n]  (bf16), z in {q,k,v,o}
__global__ __launch_bounds__(256) void conv_w_kernel(const float* __restrict__ W0,
                                                     const float* __restrict__ W1,
                                                     const float* __restrict__ W2,
                                                     const float* __restrict__ W3,
                                                     bf16* __restrict__ Wt) {
  __shared__ float t[32][33];
  const int z = blockIdx.z;
  const float* W = (z == 0) ? W0 : (z == 1) ? W1 : (z == 2) ? W2 : W3;
  const int n0 = blockIdx.x * 32, k0 = blockIdx.y * 32;
  const int tx = threadIdx.x, ty = threadIdx.y;       // (32,8)
#pragma unroll
  for (int i = 0; i < 4; ++i)
    t[ty + i * 8][tx] = W[(size_t)(k0 + ty + i * 8) * DM + n0 + tx];
  __syncthreads();
#pragma unroll
  for (int i = 0; i < 4; ++i)
    Wt[(size_t)(z * DM + n0 + ty + i * 8) * DM + k0 + tx] = (bf16)t[tx][ty + i * 8];
}

// ------------------------------------------------------------------ GEMM ----
// C[M,N] = A[M,K] * Bt[N,K]^T, K=1024, 128x128 block tile, 4 waves of 64x64,
// 16x16x32 bf16 MFMA, BK=64, global_load_lds staging with XOR-8 chunk swizzle:
//   LDS[r][c*8..] holds global chunks (c ^ (r&7)) -> ds_read_b128 spreads all
//   32 banks (2-way max, free per m136).
// MODE 0: bias + featmap(q,k parts) -> bf16 QKV (ldc=3072), LDS-coalesced.
// MODE 1: + bias -> fp32 out (ldc=1024), LDS-coalesced in 2 half-tiles.
template <int MODE>
__global__ __launch_bounds__(256) void gemm_bf16(const bf16* __restrict__ A,
                                                 const bf16* __restrict__ Bt,
                                                 void* __restrict__ Cout, int ldc,
                                                 const float* __restrict__ b0,
                                                 const float* __restrict__ b1,
                                                 const float* __restrict__ b2) {
  constexpr int K = 1024;
  constexpr int BK = 64;
  __shared__ __align__(16) char smem[32768];          // staging / epilogue union
  bf16 (*As)[BK] = (bf16(*)[BK])smem;                 // [128][64]
  bf16 (*Bs)[BK] = (bf16(*)[BK])(smem + 16384);       // [128][64]

  const int tid  = threadIdx.x;
  const int wave = tid >> 6, lane = tid & 63;
  const int quad = lane >> 4, l16 = lane & 15;
  const int bm0 = blockIdx.y * 128, bn0 = blockIdx.x * 128;
  const int wm = (wave >> 1) * 64, wn = (wave & 1) * 64;

  f32x4 acc[4][4] = {};

  // staging: wave w rows [w*32, w*32+32), 4 issues x 8 rows per matrix.
  // lane i -> row +i/8, LDS chunk i&7, GLOBAL chunk (i&7)^(i>>3) (swizzle).
  const int srow = wave * 32 + (lane >> 3);
  const int scol = ((lane & 7) ^ (lane >> 3)) * 8;    // elements
  const bf16* Ag = A  + (size_t)(bm0 + srow) * K + scol;
  const bf16* Bg = Bt + (size_t)(bn0 + srow) * K + scol;
  bf16* AsB = &As[wave * 32][0];
  bf16* BsB = &Bs[wave * 32][0];
  const int sw = l16 & 7;                             // read-side swizzle key

  for (int k0 = 0; k0 < K; k0 += BK) {
#pragma unroll
    for (int j = 0; j < 4; ++j) {
      async_cp16(Ag + (size_t)j * 8 * K, AsB + j * 8 * BK);
      async_cp16(Bg + (size_t)j * 8 * K, BsB + j * 8 * BK);
    }
    Ag += BK; Bg += BK;
    __syncthreads();                                  // drains vmcnt before barrier
#pragma unroll
    for (int kh = 0; kh < 2; ++kh) {                  // k = kh*32 + quad*8
      const int gk = kh * 4 + quad;                   // global chunk index
      s16x8 af[4], bfr[4];
#pragma unroll
      for (int mi = 0; mi < 4; ++mi)
        af[mi] = *reinterpret_cast<const s16x8*>(&As[wm + mi * 16 + l16][(gk ^ sw) * 8]);
#pragma unroll
      for (int ni = 0; ni < 4; ++ni)
        bfr[ni] = *reinterpret_cast<const s16x8*>(&Bs[wn + ni * 16 + l16][(gk ^ sw) * 8]);
#pragma unroll
      for (int mi = 0; mi < 4; ++mi)
#pragma unroll
        for (int ni = 0; ni < 4; ++ni)
          acc[mi][ni] = __builtin_amdgcn_mfma_f32_16x16x32_bf16(af[mi], bfr[ni],
                                                                acc[mi][ni], 0, 0, 0);
    }
    __syncthreads();
  }

  // epilogue. D layout: col = l16, row = quad*4 + reg (m89/m91-verified).
  if (MODE == 0) {
    const int part = bn0 >> 10;  // 0=q 1=k 2=v (128 | 1024: no straddle)
    const float* bp = (part == 0) ? b0 : (part == 1) ? b1 : b2;
    bf16* C = (bf16*)Cout;
    bf16 (*Ct)[128] = (bf16(*)[128])smem;             // 32 KB, overlays staging
#pragma unroll
    for (int ni = 0; ni < 4; ++ni) {
      const int n_l = wn + ni * 16 + l16;
      const float bias = bp[(bn0 + n_l) & 1023];
#pragma unroll
      for (int mi = 0; mi < 4; ++mi)
#pragma unroll
        for (int reg = 0; reg < 4; ++reg) {
          float v = acc[mi][ni][reg] + bias;
          if (part < 2) v = (v > 0.f) ? (v + 1.f) : __expf(v);  // elu+1
          Ct[wm + mi * 16 + quad * 4 + reg][n_l] = (bf16)v;
        }
    }
    __syncthreads();
    // coalesced store: 8 passes, 16 rows each; 16 lanes cover one row (256 B)
    const int ch = tid & 15, rbase = tid >> 4;
#pragma unroll
    for (int p = 0; p < 8; ++p) {
      const int row = p * 16 + rbase;
      *reinterpret_cast<uint4*>(C + (size_t)(bm0 + row) * ldc + bn0 + ch * 8) =
          *reinterpret_cast<const uint4*>(&Ct[row][ch * 8]);
    }
  } else {
    float* C = (float*)Cout;
    float (*Ctf)[128] = (float(*)[128])smem;          // [64][128] fp32 = 32 KB
#pragma unroll
    for (int half = 0; half < 2; ++half) {
      if ((wm >> 6) == half) {
#pragma unroll
        for (int ni = 0; ni < 4; ++ni) {
          const int n_l = wn + ni * 16 + l16;
          const float bias = b0[bn0 + n_l];
#pragma unroll
          for (int mi = 0; mi < 4; ++mi)
#pragma unroll
            for (int reg = 0; reg < 4; ++reg)
              Ctf[mi * 16 + quad * 4 + reg][n_l] = acc[mi][ni][reg] + bias;
        }
      }
      __syncthreads();
      // 64x128 fp32 = 2048 chunks of 16B; 32 chunks/row
#pragma unroll
      for (int j = 0; j < 8; ++j) {
        const int idx = j * 256 + tid;
        const int row = idx >> 5, ch = idx & 31;
        *reinterpret_cast<float4*>(C + (size_t)(bm0 + half * 64 + row) * ldc + bn0 + ch * 4) =
            *reinterpret_cast<const float4*>(&Ctf[row][ch * 4]);
      }
      __syncthreads();
    }
  }
}

// --------------------------------------------------------------- kv_ksum ----
// kv[bh][d][e] += sum_s K[s,d]*V[s,e];  ksum[bh][d] += sum_s K[s,d]
__global__ __launch_bounds__(256) void kv_ksum_kernel(const bf16* __restrict__ QKV,
                                                      float* __restrict__ kv,
                                                      float* __restrict__ ksum) {
  __shared__ bf16 Ks[128][64];
  __shared__ bf16 Vs[128][64];
  const int bh = blockIdx.y;
  const int b = bh >> 4, h = bh & 15;
  const int tid = threadIdx.x;
  const int d0 = (tid >> 4) * 4, e0 = (tid & 15) * 4;
  const size_t base = (size_t)b * SEQ * 3072;
  const int colK = 1024 + h * 64, colV = 2048 + h * 64;

  float acc[4][4] = {};
  float ks = 0.f;

  for (int cc = 0; cc < 2; ++cc) {
    const int s0 = blockIdx.x * 256 + cc * 128;
#pragma unroll
    for (int i = 0; i < 4; ++i) {
      const int c = tid + i * 256;
      const int row = c >> 3, off = (c & 7) * 8;
      const size_t roff = base + (size_t)(s0 + row) * 3072;
      *reinterpret_cast<uint4*>(&Ks[row][off]) =
          *reinterpret_cast<const uint4*>(QKV + roff + colK + off);
      *reinterpret_cast<uint4*>(&Vs[row][off]) =
          *reinterpret_cast<const uint4*>(QKV + roff + colV + off);
    }
    __syncthreads();
#pragma unroll 4
    for (int s = 0; s < 128; ++s) {
      bf16x4 kk = *reinterpret_cast<const bf16x4*>(&Ks[s][d0]);
      bf16x4 vv = *reinterpret_cast<const bf16x4*>(&Vs[s][e0]);
      float kd[4], ve[4];
#pragma unroll
      for (int j = 0; j < 4; ++j) { kd[j] = (float)kk[j]; ve[j] = (float)vv[j]; }
#pragma unroll
      for (int i = 0; i < 4; ++i)
#pragma unroll
        for (int j = 0; j < 4; ++j) acc[i][j] += kd[i] * ve[j];
    }
    if (tid < 64) {
#pragma unroll 8
      for (int s = 0; s < 128; ++s) ks += (float)Ks[s][tid];
    }
    __syncthreads();
  }
#pragma unroll
  for (int i = 0; i < 4; ++i)
#pragma unroll
    for (int j = 0; j < 4; ++j)
      atomicAdd(&kv[(size_t)bh * 4096 + (d0 + i) * 64 + e0 + j], acc[i][j]);
  if (tid < 64) atomicAdd(&ksum[bh * 64 + tid], ks);
}

// ------------------------------------------------------------------ attn ----
// ATT[b,s, h*64+e] = (sum_d q[s,d]*kv[d,e]) / (q[s,:].ksum + eps)   (bf16 out)
__global__ __launch_bounds__(256) void attn_kernel(const bf16* __restrict__ QKV,
                                                   const float* __restrict__ kv,
                                                   const float* __restrict__ ksum,
                                                   bf16* __restrict__ ATT) {
  __shared__ bf16 qs[128][72];
  __shared__ float kvs[64][64];
  __shared__ float zr[128];
  __shared__ float kss[64];
  const int bh = blockIdx.y;
  const int b = bh >> 4, h = bh & 15;
  const int s0 = blockIdx.x * 128;
  const int tid = threadIdx.x, wave = tid >> 6, lane = tid & 63;
  const size_t base = (size_t)b * SEQ * 3072;
  const int colQ = h * 64;

#pragma unroll
  for (int i = 0; i < 4; ++i) {
    const int c = tid + i * 256;
    const int row = c >> 3, off = (c & 7) * 8;
    *reinterpret_cast<uint4*>(&qs[row][off]) =
        *reinterpret_cast<const uint4*>(QKV + base + (size_t)(s0 + row) * 3072 + colQ + off);
  }
  const float* kvg = kv + (size_t)bh * 4096;
#pragma unroll
  for (int i = 0; i < 4; ++i) {
    const int c = tid + i * 256;
    const int row = c >> 4, off = (c & 15) * 4;
    *reinterpret_cast<float4*>(&kvs[row][off]) =
        *reinterpret_cast<const float4*>(kvg + row * 64 + off);
  }
  if (tid < 64) kss[tid] = ksum[bh * 64 + tid];
  __syncthreads();

  if (tid < 128) {
    float z = 0.f;
#pragma unroll
    for (int d = 0; d < 64; d += 4) {
      bf16x4 q4 = *reinterpret_cast<const bf16x4*>(&qs[tid][d]);
      z += (float)q4[0] * kss[d] + (float)q4[1] * kss[d + 1] +
           (float)q4[2] * kss[d + 2] + (float)q4[3] * kss[d + 3];
    }
    zr[tid] = 1.0f / (z + EPSV);
  }
  __syncthreads();

  const int e0 = (lane & 15) * 4;
  for (int it = 0; it < 2; ++it) {
    const int rb = it * 64 + wave * 16 + (lane >> 4) * 4;
    float acc[4][4] = {};
    for (int d = 0; d < 64; ++d) {
      const float4 kvv = *reinterpret_cast<const float4*>(&kvs[d][e0]);
#pragma unroll
      for (int rr = 0; rr < 4; ++rr) {
        const float qv = (float)qs[rb + rr][d];
        acc[rr][0] += qv * kvv.x; acc[rr][1] += qv * kvv.y;
        acc[rr][2] += qv * kvv.z; acc[rr][3] += qv * kvv.w;
      }
    }
#pragma unroll
    for (int rr = 0; rr < 4; ++rr) {
      const float zi = zr[rb + rr];
      bf16x4 o;
      o[0] = (bf16)(acc[rr][0] * zi); o[1] = (bf16)(acc[rr][1] * zi);
      o[2] = (bf16)(acc[rr][2] * zi); o[3] = (bf16)(acc[rr][3] * zi);
      *reinterpret_cast<bf16x4*>(ATT + ((size_t)b * SEQ + s0 + rb + rr) * DM + h * 64 + e0) = o;
    }
  }
}

// ---------------------------------------------------------------- launch ----
extern "C" void kernel_launch(void* const* d_in, const int* in_sizes, int n_in,
                              void* d_out, int out_size, void* d_ws, size_t ws_size,
                              hipStream_t stream) {
  const float* x  = (const float*)d_in[0];
  const float* Wq = (const float*)d_in[1];
  const float* bq = (const float*)d_in[2];
  const float* Wk = (const float*)d_in[3];
  const float* bk = (const float*)d_in[4];
  const float* Wv = (const float*)d_in[5];
  const float* bv = (const float*)d_in[6];
  const float* Wo = (const float*)d_in[7];
  const float* bo = (const float*)d_in[8];
  float* out = (float*)d_out;

  char* ws = (char*)d_ws;
  bf16*  Xb   = (bf16*)ws;   ws += (size_t)MROWS * DM * 2;        // 32 MB
  bf16*  Wt   = (bf16*)ws;   ws += (size_t)4 * DM * DM * 2;       // 8 MB (qkv^T + o^T)
  bf16*  QKV  = (bf16*)ws;   ws += (size_t)MROWS * 3 * DM * 2;    // 96 MB
  bf16*  ATT  = (bf16*)ws;   ws += (size_t)MROWS * DM * 2;        // 32 MB
  float* kvp  = (float*)ws;  ws += (size_t)64 * 4096 * 4;         // 1 MB
  float* ksum = (float*)ws;  ws += (size_t)64 * 64 * 4;           // 16 KB

  (void)hipMemsetAsync(kvp, 0, (size_t)64 * 4096 * 4 + (size_t)64 * 64 * 4, stream);

  conv_x_kernel<<<MROWS * DM / 1024, 256, 0, stream>>>(x, Xb);
  conv_w_kernel<<<dim3(32, 32, 4), dim3(32, 8), 0, stream>>>(Wq, Wk, Wv, Wo, Wt);
  gemm_bf16<0><<<dim3(24, 128), 256, 0, stream>>>(Xb, Wt, QKV, 3 * DM, bq, bk, bv);
  kv_ksum_kernel<<<dim3(16, 64), 256, 0, stream>>>(QKV, kvp, ksum);
  attn_kernel<<<dim3(32, 64), 256, 0, stream>>>(QKV, kvp, ksum, ATT);
  gemm_bf16<1><<<dim3(8, 128), 256, 0, stream>>>(ATT, Wt + (size_t)3 * DM * DM, out, DM, bo, bo, bo);
}

// Round 4
// 433.500 us; speedup vs baseline: 1.0383x; 1.0254x over previous
//
#include <hip/hip_runtime.h>

// ---------------------------------------------------------------------------
// LinearAttention: out = (featmap(xWq+bq) @ [K^T V]) / (q . sum K + eps) @ Wo + bo
// featmap(t) = elu(t)+1 = t>0 ? t+1 : exp(t)
// B=4, S=4096, D_MODEL=1024, H=16, DK=64. Inputs fp32; compute in bf16 MFMA.
// R4: attn inner loop vectorized (b64 q / b128 kv reads, was scalar u16 —
//     LDS-issue-bound); kv_ksum folds ksum into main loop, 512-row blocks.
// ---------------------------------------------------------------------------

typedef __bf16 bf16;
typedef float  f32x4  __attribute__((ext_vector_type(4)));
typedef short  s16x8  __attribute__((ext_vector_type(8)));   // 8 bf16 = 4 VGPRs (MFMA A/B frag)
typedef bf16   bf16x4 __attribute__((ext_vector_type(4)));

#define BATCH 4
#define SEQ   4096
#define DM    1024
#define NH    16
#define DK    64
#define MROWS (BATCH*SEQ)            // 16384
#define EPSV  1e-6f

// async 16B global->LDS DMA. LDS dest is wave-uniform base; HW writes
// base + lane*16.
__device__ __forceinline__ void async_cp16(const bf16* g, bf16* l) {
  __builtin_amdgcn_global_load_lds((const __attribute__((address_space(1))) void*)g,
                                   (__attribute__((address_space(3))) void*)l,
                                   16, 0, 0);
}

// ---------------------------------------------------------------- conv_x ----
__global__ __launch_bounds__(256) void conv_x_kernel(const float* __restrict__ x,
                                                     bf16* __restrict__ xb) {
  int i = (blockIdx.x * 256 + threadIdx.x) * 4;
  float4 f = *reinterpret_cast<const float4*>(x + i);
  bf16x4 o;
  o[0] = (bf16)f.x; o[1] = (bf16)f.y; o[2] = (bf16)f.z; o[3] = (bf16)f.w;
  *reinterpret_cast<bf16x4*>(xb + i) = o;
}

// ------------------------------------------------------- conv_w (transpose) -
// Wt[z*1024 + n][k] = Wz[k][n]  (bf16), z in {q,k,v,o}
__global__ __launch_bounds__(256) void conv_w_kernel(const float* __restrict__ W0,
                                                     const float* __restrict__ W1,
                                                     const float* __restrict__ W2,
                                                     const float* __restrict__ W3,
                                                     bf16* __restrict__ Wt) {
  __shared__ float t[32][33];
  const int z = blockIdx.z;
  const float* W = (z == 0) ? W0 : (z == 1) ? W1 : (z == 2) ? W2 : W3;
  const int n0 = blockIdx.x * 32, k0 = blockIdx.y * 32;
  const int tx = threadIdx.x, ty = threadIdx.y;       // (32,8)
#pragma unroll
  for (int i = 0; i < 4; ++i)
    t[ty + i * 8][tx] = W[(size_t)(k0 + ty + i * 8) * DM + n0 + tx];
  __syncthreads();
#pragma unroll
  for (int i = 0; i < 4; ++i)
    Wt[(size_t)(z * DM + n0 + ty + i * 8) * DM + k0 + tx] = (bf16)t[tx][ty + i * 8];
}

// ------------------------------------------------------------------ GEMM ----
// C[M,N] = A[M,K] * Bt[N,K]^T, K=1024, 128x128 block tile, 4 waves of 64x64,
// 16x16x32 bf16 MFMA, BK=64, global_load_lds staging with XOR-8 chunk swizzle.
// MODE 0: bias + featmap(q,k parts) -> bf16 QKV (ldc=3072), LDS-coalesced.
// MODE 1: + bias -> fp32 out (ldc=1024), LDS-coalesced in 2 half-tiles.
template <int MODE>
__global__ __launch_bounds__(256) void gemm_bf16(const bf16* __restrict__ A,
                                                 const bf16* __restrict__ Bt,
                                                 void* __restrict__ Cout, int ldc,
                                                 const float* __restrict__ b0,
                                                 const float* __restrict__ b1,
                                                 const float* __restrict__ b2) {
  constexpr int K = 1024;
  constexpr int BK = 64;
  __shared__ __align__(16) char smem[32768];          // staging / epilogue union
  bf16 (*As)[BK] = (bf16(*)[BK])smem;                 // [128][64]
  bf16 (*Bs)[BK] = (bf16(*)[BK])(smem + 16384);       // [128][64]

  const int tid  = threadIdx.x;
  const int wave = tid >> 6, lane = tid & 63;
  const int quad = lane >> 4, l16 = lane & 15;
  const int bm0 = blockIdx.y * 128, bn0 = blockIdx.x * 128;
  const int wm = (wave >> 1) * 64, wn = (wave & 1) * 64;

  f32x4 acc[4][4] = {};

  // staging: wave w rows [w*32, w*32+32), 4 issues x 8 rows per matrix.
  // lane i -> row +i/8, LDS chunk i&7, GLOBAL chunk (i&7)^(i>>3) (swizzle).
  const int srow = wave * 32 + (lane >> 3);
  const int scol = ((lane & 7) ^ (lane >> 3)) * 8;    // elements
  const bf16* Ag = A  + (size_t)(bm0 + srow) * K + scol;
  const bf16* Bg = Bt + (size_t)(bn0 + srow) * K + scol;
  bf16* AsB = &As[wave * 32][0];
  bf16* BsB = &Bs[wave * 32][0];
  const int sw = l16 & 7;                             // read-side swizzle key

  for (int k0 = 0; k0 < K; k0 += BK) {
#pragma unroll
    for (int j = 0; j < 4; ++j) {
      async_cp16(Ag + (size_t)j * 8 * K, AsB + j * 8 * BK);
      async_cp16(Bg + (size_t)j * 8 * K, BsB + j * 8 * BK);
    }
    Ag += BK; Bg += BK;
    __syncthreads();                                  // drains vmcnt before barrier
#pragma unroll
    for (int kh = 0; kh < 2; ++kh) {                  // k = kh*32 + quad*8
      const int gk = kh * 4 + quad;                   // global chunk index
      s16x8 af[4], bfr[4];
#pragma unroll
      for (int mi = 0; mi < 4; ++mi)
        af[mi] = *reinterpret_cast<const s16x8*>(&As[wm + mi * 16 + l16][(gk ^ sw) * 8]);
#pragma unroll
      for (int ni = 0; ni < 4; ++ni)
        bfr[ni] = *reinterpret_cast<const s16x8*>(&Bs[wn + ni * 16 + l16][(gk ^ sw) * 8]);
#pragma unroll
      for (int mi = 0; mi < 4; ++mi)
#pragma unroll
        for (int ni = 0; ni < 4; ++ni)
          acc[mi][ni] = __builtin_amdgcn_mfma_f32_16x16x32_bf16(af[mi], bfr[ni],
                                                                acc[mi][ni], 0, 0, 0);
    }
    __syncthreads();
  }

  // epilogue. D layout: col = l16, row = quad*4 + reg (m89/m91-verified).
  if (MODE == 0) {
    const int part = bn0 >> 10;  // 0=q 1=k 2=v (128 | 1024: no straddle)
    const float* bp = (part == 0) ? b0 : (part == 1) ? b1 : b2;
    bf16* C = (bf16*)Cout;
    bf16 (*Ct)[128] = (bf16(*)[128])smem;             // 32 KB, overlays staging
#pragma unroll
    for (int ni = 0; ni < 4; ++ni) {
      const int n_l = wn + ni * 16 + l16;
      const float bias = bp[(bn0 + n_l) & 1023];
#pragma unroll
      for (int mi = 0; mi < 4; ++mi)
#pragma unroll
        for (int reg = 0; reg < 4; ++reg) {
          float v = acc[mi][ni][reg] + bias;
          if (part < 2) v = (v > 0.f) ? (v + 1.f) : __expf(v);  // elu+1
          Ct[wm + mi * 16 + quad * 4 + reg][n_l] = (bf16)v;
        }
    }
    __syncthreads();
    // coalesced store: 8 passes, 16 rows each; 16 lanes cover one row (256 B)
    const int ch = tid & 15, rbase = tid >> 4;
#pragma unroll
    for (int p = 0; p < 8; ++p) {
      const int row = p * 16 + rbase;
      *reinterpret_cast<uint4*>(C + (size_t)(bm0 + row) * ldc + bn0 + ch * 8) =
          *reinterpret_cast<const uint4*>(&Ct[row][ch * 8]);
    }
  } else {
    float* C = (float*)Cout;
    float (*Ctf)[128] = (float(*)[128])smem;          // [64][128] fp32 = 32 KB
#pragma unroll
    for (int half = 0; half < 2; ++half) {
      if ((wm >> 6) == half) {
#pragma unroll
        for (int ni = 0; ni < 4; ++ni) {
          const int n_l = wn + ni * 16 + l16;
          const float bias = b0[bn0 + n_l];
#pragma unroll
          for (int mi = 0; mi < 4; ++mi)
#pragma unroll
            for (int reg = 0; reg < 4; ++reg)
              Ctf[mi * 16 + quad * 4 + reg][n_l] = acc[mi][ni][reg] + bias;
        }
      }
      __syncthreads();
      // 64x128 fp32 = 2048 chunks of 16B; 32 chunks/row
#pragma unroll
      for (int j = 0; j < 8; ++j) {
        const int idx = j * 256 + tid;
        const int row = idx >> 5, ch = idx & 31;
        *reinterpret_cast<float4*>(C + (size_t)(bm0 + half * 64 + row) * ldc + bn0 + ch * 4) =
            *reinterpret_cast<const float4*>(&Ctf[row][ch * 4]);
      }
      __syncthreads();
    }
  }
}

// --------------------------------------------------------------- kv_ksum ----
// kv[bh][d][e] += sum_s K[s,d]*V[s,e];  ksum[bh][d] += sum_s K[s,d]
// grid (8 s-chunks of 512, 64 bh); thread owns 4x4 (d,e); ksum folded in-loop
// (redundant across e-groups; only e-group 0 commits).
__global__ __launch_bounds__(256) void kv_ksum_kernel(const bf16* __restrict__ QKV,
                                                      float* __restrict__ kv,
                                                      float* __restrict__ ksum) {
  __shared__ bf16 Ks[128][64];
  __shared__ bf16 Vs[128][64];
  const int bh = blockIdx.y;
  const int b = bh >> 4, h = bh & 15;
  const int tid = threadIdx.x;
  const int d0 = (tid >> 4) * 4, e0 = (tid & 15) * 4;
  const size_t base = (size_t)b * SEQ * 3072;
  const int colK = 1024 + h * 64, colV = 2048 + h * 64;

  float acc[4][4] = {};
  float ks4[4] = {};

  for (int cc = 0; cc < 4; ++cc) {
    const int s0 = blockIdx.x * 512 + cc * 128;
#pragma unroll
    for (int i = 0; i < 4; ++i) {
      const int c = tid + i * 256;
      const int row = c >> 3, off = (c & 7) * 8;
      const size_t roff = base + (size_t)(s0 + row) * 3072;
      *reinterpret_cast<uint4*>(&Ks[row][off]) =
          *reinterpret_cast<const uint4*>(QKV + roff + colK + off);
      *reinterpret_cast<uint4*>(&Vs[row][off]) =
          *reinterpret_cast<const uint4*>(QKV + roff + colV + off);
    }
    __syncthreads();
#pragma unroll 4
    for (int s = 0; s < 128; ++s) {
      bf16x4 kk = *reinterpret_cast<const bf16x4*>(&Ks[s][d0]);
      bf16x4 vv = *reinterpret_cast<const bf16x4*>(&Vs[s][e0]);
      float kd[4], ve[4];
#pragma unroll
      for (int j = 0; j < 4; ++j) { kd[j] = (float)kk[j]; ve[j] = (float)vv[j]; }
#pragma unroll
      for (int i = 0; i < 4; ++i) {
        ks4[i] += kd[i];
#pragma unroll
        for (int j = 0; j < 4; ++j) acc[i][j] += kd[i] * ve[j];
      }
    }
    __syncthreads();
  }
#pragma unroll
  for (int i = 0; i < 4; ++i)
#pragma unroll
    for (int j = 0; j < 4; ++j)
      atomicAdd(&kv[(size_t)bh * 4096 + (d0 + i) * 64 + e0 + j], acc[i][j]);
  if ((tid & 15) == 0) {
#pragma unroll
    for (int i = 0; i < 4; ++i)
      atomicAdd(&ksum[bh * 64 + d0 + i], ks4[i]);
  }
}

// ------------------------------------------------------------------ attn ----
// ATT[b,s, h*64+e] = (sum_d q[s,d]*kv[d,e]) / (q[s,:].ksum + eps)   (bf16 out)
// Inner loop vectorized: b64 q-reads, b128 kv-reads (was scalar u16 — LDS-bound)
__global__ __launch_bounds__(256) void attn_kernel(const bf16* __restrict__ QKV,
                                                   const float* __restrict__ kv,
                                                   const float* __restrict__ ksum,
                                                   bf16* __restrict__ ATT) {
  __shared__ bf16 qs[128][72];
  __shared__ float kvs[64][64];
  __shared__ float zr[128];
  __shared__ float kss[64];
  const int bh = blockIdx.y;
  const int b = bh >> 4, h = bh & 15;
  const int s0 = blockIdx.x * 128;
  const int tid = threadIdx.x, wave = tid >> 6, lane = tid & 63;
  const size_t base = (size_t)b * SEQ * 3072;
  const int colQ = h * 64;

#pragma unroll
  for (int i = 0; i < 4; ++i) {
    const int c = tid + i * 256;
    const int row = c >> 3, off = (c & 7) * 8;
    *reinterpret_cast<uint4*>(&qs[row][off]) =
        *reinterpret_cast<const uint4*>(QKV + base + (size_t)(s0 + row) * 3072 + colQ + off);
  }
  const float* kvg = kv + (size_t)bh * 4096;
#pragma unroll
  for (int i = 0; i < 4; ++i) {
    const int c = tid + i * 256;
    const int row = c >> 4, off = (c & 15) * 4;
    *reinterpret_cast<float4*>(&kvs[row][off]) =
        *reinterpret_cast<const float4*>(kvg + row * 64 + off);
  }
  if (tid < 64) kss[tid] = ksum[bh * 64 + tid];
  __syncthreads();

  if (tid < 128) {
    float z = 0.f;
#pragma unroll
    for (int d = 0; d < 64; d += 4) {
      bf16x4 q4 = *reinterpret_cast<const bf16x4*>(&qs[tid][d]);
      z += (float)q4[0] * kss[d] + (float)q4[1] * kss[d + 1] +
           (float)q4[2] * kss[d + 2] + (float)q4[3] * kss[d + 3];
    }
    zr[tid] = 1.0f / (z + EPSV);
  }
  __syncthreads();

  const int e0 = (lane & 15) * 4;
  for (int it = 0; it < 2; ++it) {
    const int rb = it * 64 + wave * 16 + (lane >> 4) * 4;
    float acc[4][4] = {};
#pragma unroll 4
    for (int d4 = 0; d4 < 64; d4 += 4) {
      bf16x4 q4[4];
      float4 kv4[4];
#pragma unroll
      for (int rr = 0; rr < 4; ++rr)
        q4[rr] = *reinterpret_cast<const bf16x4*>(&qs[rb + rr][d4]);
#pragma unroll
      for (int j = 0; j < 4; ++j)
        kv4[j] = *reinterpret_cast<const float4*>(&kvs[d4 + j][e0]);
#pragma unroll
      for (int rr = 0; rr < 4; ++rr) {
#pragma unroll
        for (int j = 0; j < 4; ++j) {
          const float qv = (float)q4[rr][j];
          acc[rr][0] += qv * kv4[j].x; acc[rr][1] += qv * kv4[j].y;
          acc[rr][2] += qv * kv4[j].z; acc[rr][3] += qv * kv4[j].w;
        }
      }
    }
#pragma unroll
    for (int rr = 0; rr < 4; ++rr) {
      const float zi = zr[rb + rr];
      bf16x4 o;
      o[0] = (bf16)(acc[rr][0] * zi); o[1] = (bf16)(acc[rr][1] * zi);
      o[2] = (bf16)(acc[rr][2] * zi); o[3] = (bf16)(acc[rr][3] * zi);
      *reinterpret_cast<bf16x4*>(ATT + ((size_t)b * SEQ + s0 + rb + rr) * DM + h * 64 + e0) = o;
    }
  }
}

// ---------------------------------------------------------------- launch ----
extern "C" void kernel_launch(void* const* d_in, const int* in_sizes, int n_in,
                              void* d_out, int out_size, void* d_ws, size_t ws_size,
                              hipStream_t stream) {
  const float* x  = (const float*)d_in[0];
  const float* Wq = (const float*)d_in[1];
  const float* bq = (const float*)d_in[2];
  const float* Wk = (const float*)d_in[3];
  const float* bk = (const float*)d_in[4];
  const float* Wv = (const float*)d_in[5];
  const float* bv = (const float*)d_in[6];
  const float* Wo = (const float*)d_in[7];
  const float* bo = (const float*)d_in[8];
  float* out = (float*)d_out;

  char* ws = (char*)d_ws;
  bf16*  Xb   = (bf16*)ws;   ws += (size_t)MROWS * DM * 2;        // 32 MB
  bf16*  Wt   = (bf16*)ws;   ws += (size_t)4 * DM * DM * 2;       // 8 MB (qkv^T + o^T)
  bf16*  QKV  = (bf16*)ws;   ws += (size_t)MROWS * 3 * DM * 2;    // 96 MB
  bf16*  ATT  = (bf16*)ws;   ws += (size_t)MROWS * DM * 2;        // 32 MB
  float* kvp  = (float*)ws;  ws += (size_t)64 * 4096 * 4;         // 1 MB
  float* ksum = (float*)ws;  ws += (size_t)64 * 64 * 4;           // 16 KB

  (void)hipMemsetAsync(kvp, 0, (size_t)64 * 4096 * 4 + (size_t)64 * 64 * 4, stream);

  conv_x_kernel<<<MROWS * DM / 1024, 256, 0, stream>>>(x, Xb);
  conv_w_kernel<<<dim3(32, 32, 4), dim3(32, 8), 0, stream>>>(Wq, Wk, Wv, Wo, Wt);
  gemm_bf16<0><<<dim3(24, 128), 256, 0, stream>>>(Xb, Wt, QKV, 3 * DM, bq, bk, bv);
  kv_ksum_kernel<<<dim3(8, 64), 256, 0, stream>>>(QKV, kvp, ksum);
  attn_kernel<<<dim3(32, 64), 256, 0, stream>>>(QKV, kvp, ksum, ATT);
  gemm_bf16<1><<<dim3(8, 128), 256, 0, stream>>>(ATT, Wt + (size_t)3 * DM * DM, out, DM, bo, bo, bo);
}

// Round 6
// 403.241 us; speedup vs baseline: 1.1162x; 1.0750x over previous
//
#include <hip/hip_runtime.h>

// ---------------------------------------------------------------------------
// LinearAttention: out = (featmap(xWq+bq) @ [K^T V]) / (q . sum K + eps) @ Wo + bo
// featmap(t) = elu(t)+1 = t>0 ? t+1 : exp(t)
// B=4, S=4096, D_MODEL=1024, H=16, DK=64. Inputs fp32; compute in bf16 MFMA.
// R6: fix conv_w store-loop overrun (512 chunks, not 1024 — was clobbering
//     neighbor tiles with uninit LDS). attn stays on MFMA (P^T = kvT @ q^T).
// ---------------------------------------------------------------------------

typedef __bf16 bf16;
typedef float  f32x4  __attribute__((ext_vector_type(4)));
typedef short  s16x8  __attribute__((ext_vector_type(8)));   // 8 bf16 = 4 VGPRs (MFMA A/B frag)
typedef bf16   bf16x4 __attribute__((ext_vector_type(4)));

#define BATCH 4
#define SEQ   4096
#define DM    1024
#define NH    16
#define DK    64
#define MROWS (BATCH*SEQ)            // 16384
#define EPSV  1e-6f

// async 16B global->LDS DMA. LDS dest is wave-uniform base; HW writes
// base + lane*16.
__device__ __forceinline__ void async_cp16(const bf16* g, bf16* l) {
  __builtin_amdgcn_global_load_lds((const __attribute__((address_space(1))) void*)g,
                                   (__attribute__((address_space(3))) void*)l,
                                   16, 0, 0);
}

// ---------------------------------------------------------------- conv_x ----
__global__ __launch_bounds__(256) void conv_x_kernel(const float* __restrict__ x,
                                                     bf16* __restrict__ xb) {
  int i = (blockIdx.x * 256 + threadIdx.x) * 4;
  float4 f = *reinterpret_cast<const float4*>(x + i);
  bf16x4 o;
  o[0] = (bf16)f.x; o[1] = (bf16)f.y; o[2] = (bf16)f.z; o[3] = (bf16)f.w;
  *reinterpret_cast<bf16x4*>(xb + i) = o;
}

// ------------------------------------------------------- conv_w (transpose) -
// Wt[z*1024 + n][k] = Wz[k][n]  (bf16), z in {q,k,v,o}. 64x64 tiles,
// transpose via bf16 LDS scatter, 128B full-line coalesced stores.
__global__ __launch_bounds__(256) void conv_w_kernel(const float* __restrict__ W0,
                                                     const float* __restrict__ W1,
                                                     const float* __restrict__ W2,
                                                     const float* __restrict__ W3,
                                                     bf16* __restrict__ Wt) {
  __shared__ bf16 tt[64][72];                         // [n][k], pad 72 (16B-aligned rows)
  const int z = blockIdx.z;
  const float* W = (z == 0) ? W0 : (z == 1) ? W1 : (z == 2) ? W2 : W3;
  const int n0 = blockIdx.x * 64, k0 = blockIdx.y * 64;
  const int tid = threadIdx.x;
#pragma unroll
  for (int i = 0; i < 4; ++i) {                       // 1024 float4 chunks (64x16)
    const int c = tid + i * 256;
    const int krow = c >> 4, nch = c & 15;
    float4 f = *reinterpret_cast<const float4*>(W + (size_t)(k0 + krow) * DM + n0 + nch * 4);
    tt[nch * 4 + 0][krow] = (bf16)f.x;
    tt[nch * 4 + 1][krow] = (bf16)f.y;
    tt[nch * 4 + 2][krow] = (bf16)f.z;
    tt[nch * 4 + 3][krow] = (bf16)f.w;
  }
  __syncthreads();
#pragma unroll
  for (int i = 0; i < 2; ++i) {                       // 512 chunks: 64 rows x 8x16B
    const int c = tid + i * 256;
    const int nrow = c >> 3, kch = c & 7;
    *reinterpret_cast<uint4*>(Wt + (size_t)(z * DM + n0 + nrow) * DM + k0 + kch * 8) =
        *reinterpret_cast<const uint4*>(&tt[nrow][kch * 8]);
  }
}

// ------------------------------------------------------------------ GEMM ----
// C[M,N] = A[M,K] * Bt[N,K]^T, K=1024, 128x128 block tile, 4 waves of 64x64,
// 16x16x32 bf16 MFMA, BK=64, global_load_lds staging with XOR-8 chunk swizzle.
// MODE 0: bias + featmap(q,k parts) -> bf16 QKV (ldc=3072), LDS-coalesced.
// MODE 1: + bias -> fp32 out (ldc=1024), LDS-coalesced in 2 half-tiles.
template <int MODE>
__global__ __launch_bounds__(256) void gemm_bf16(const bf16* __restrict__ A,
                                                 const bf16* __restrict__ Bt,
                                                 void* __restrict__ Cout, int ldc,
                                                 const float* __restrict__ b0,
                                                 const float* __restrict__ b1,
                                                 const float* __restrict__ b2) {
  constexpr int K = 1024;
  constexpr int BK = 64;
  __shared__ __align__(16) char smem[32768];          // staging / epilogue union
  bf16 (*As)[BK] = (bf16(*)[BK])smem;                 // [128][64]
  bf16 (*Bs)[BK] = (bf16(*)[BK])(smem + 16384);       // [128][64]

  const int tid  = threadIdx.x;
  const int wave = tid >> 6, lane = tid & 63;
  const int quad = lane >> 4, l16 = lane & 15;
  const int bm0 = blockIdx.y * 128, bn0 = blockIdx.x * 128;
  const int wm = (wave >> 1) * 64, wn = (wave & 1) * 64;

  f32x4 acc[4][4] = {};

  // staging: wave w rows [w*32, w*32+32), 4 issues x 8 rows per matrix.
  // lane i -> row +i/8, LDS chunk i&7, GLOBAL chunk (i&7)^(i>>3) (swizzle).
  const int srow = wave * 32 + (lane >> 3);
  const int scol = ((lane & 7) ^ (lane >> 3)) * 8;    // elements
  const bf16* Ag = A  + (size_t)(bm0 + srow) * K + scol;
  const bf16* Bg = Bt + (size_t)(bn0 + srow) * K + scol;
  bf16* AsB = &As[wave * 32][0];
  bf16* BsB = &Bs[wave * 32][0];
  const int sw = l16 & 7;                             // read-side swizzle key

  for (int k0 = 0; k0 < K; k0 += BK) {
#pragma unroll
    for (int j = 0; j < 4; ++j) {
      async_cp16(Ag + (size_t)j * 8 * K, AsB + j * 8 * BK);
      async_cp16(Bg + (size_t)j * 8 * K, BsB + j * 8 * BK);
    }
    Ag += BK; Bg += BK;
    __syncthreads();                                  // drains vmcnt before barrier
#pragma unroll
    for (int kh = 0; kh < 2; ++kh) {                  // k = kh*32 + quad*8
      const int gk = kh * 4 + quad;                   // global chunk index
      s16x8 af[4], bfr[4];
#pragma unroll
      for (int mi = 0; mi < 4; ++mi)
        af[mi] = *reinterpret_cast<const s16x8*>(&As[wm + mi * 16 + l16][(gk ^ sw) * 8]);
#pragma unroll
      for (int ni = 0; ni < 4; ++ni)
        bfr[ni] = *reinterpret_cast<const s16x8*>(&Bs[wn + ni * 16 + l16][(gk ^ sw) * 8]);
#pragma unroll
      for (int mi = 0; mi < 4; ++mi)
#pragma unroll
        for (int ni = 0; ni < 4; ++ni)
          acc[mi][ni] = __builtin_amdgcn_mfma_f32_16x16x32_bf16(af[mi], bfr[ni],
                                                                acc[mi][ni], 0, 0, 0);
    }
    __syncthreads();
  }

  // epilogue. D layout: col = l16, row = quad*4 + reg (m89/m91-verified).
  if (MODE == 0) {
    const int part = bn0 >> 10;  // 0=q 1=k 2=v (128 | 1024: no straddle)
    const float* bp = (part == 0) ? b0 : (part == 1) ? b1 : b2;
    bf16* C = (bf16*)Cout;
    bf16 (*Ct)[128] = (bf16(*)[128])smem;             // 32 KB, overlays staging
#pragma unroll
    for (int ni = 0; ni < 4; ++ni) {
      const int n_l = wn + ni * 16 + l16;
      const float bias = bp[(bn0 + n_l) & 1023];
#pragma unroll
      for (int mi = 0; mi < 4; ++mi)
#pragma unroll
        for (int reg = 0; reg < 4; ++reg) {
          float v = acc[mi][ni][reg] + bias;
          if (part < 2) v = (v > 0.f) ? (v + 1.f) : __expf(v);  // elu+1
          Ct[wm + mi * 16 + quad * 4 + reg][n_l] = (bf16)v;
        }
    }
    __syncthreads();
    // coalesced store: 8 passes, 16 rows each; 16 lanes cover one row (256 B)
    const int ch = tid & 15, rbase = tid >> 4;
#pragma unroll
    for (int p = 0; p < 8; ++p) {
      const int row = p * 16 + rbase;
      *reinterpret_cast<uint4*>(C + (size_t)(bm0 + row) * ldc + bn0 + ch * 8) =
          *reinterpret_cast<const uint4*>(&Ct[row][ch * 8]);
    }
  } else {
    float* C = (float*)Cout;
    float (*Ctf)[128] = (float(*)[128])smem;          // [64][128] fp32 = 32 KB
#pragma unroll
    for (int half = 0; half < 2; ++half) {
      if ((wm >> 6) == half) {
#pragma unroll
        for (int ni = 0; ni < 4; ++ni) {
          const int n_l = wn + ni * 16 + l16;
          const float bias = b0[bn0 + n_l];
#pragma unroll
          for (int mi = 0; mi < 4; ++mi)
#pragma unroll
            for (int reg = 0; reg < 4; ++reg)
              Ctf[mi * 16 + quad * 4 + reg][n_l] = acc[mi][ni][reg] + bias;
        }
      }
      __syncthreads();
      // 64x128 fp32 = 2048 chunks of 16B; 32 chunks/row
#pragma unroll
      for (int j = 0; j < 8; ++j) {
        const int idx = j * 256 + tid;
        const int row = idx >> 5, ch = idx & 31;
        *reinterpret_cast<float4*>(C + (size_t)(bm0 + half * 64 + row) * ldc + bn0 + ch * 4) =
            *reinterpret_cast<const float4*>(&Ctf[row][ch * 4]);
      }
      __syncthreads();
    }
  }
}

// --------------------------------------------------------------- kv_ksum ----
// kvT[bh][e][d] += sum_s K[s,d]*V[s,e]  (TRANSPOSED accumulation for attn's
// MFMA A-operand);  ksum[bh][d] += sum_s K[s,d]
// grid (8 s-chunks of 512, 64 bh); thread owns 4x4 (d,e); ksum folded in-loop.
__global__ __launch_bounds__(256) void kv_ksum_kernel(const bf16* __restrict__ QKV,
                                                      float* __restrict__ kvT,
                                                      float* __restrict__ ksum) {
  __shared__ bf16 Ks[128][64];
  __shared__ bf16 Vs[128][64];
  const int bh = blockIdx.y;
  const int b = bh >> 4, h = bh & 15;
  const int tid = threadIdx.x;
  const int d0 = (tid >> 4) * 4, e0 = (tid & 15) * 4;
  const size_t base = (size_t)b * SEQ * 3072;
  const int colK = 1024 + h * 64, colV = 2048 + h * 64;

  float acc[4][4] = {};
  float ks4[4] = {};

  for (int cc = 0; cc < 4; ++cc) {
    const int s0 = blockIdx.x * 512 + cc * 128;
#pragma unroll
    for (int i = 0; i < 4; ++i) {
      const int c = tid + i * 256;
      const int row = c >> 3, off = (c & 7) * 8;
      const size_t roff = base + (size_t)(s0 + row) * 3072;
      *reinterpret_cast<uint4*>(&Ks[row][off]) =
          *reinterpret_cast<const uint4*>(QKV + roff + colK + off);
      *reinterpret_cast<uint4*>(&Vs[row][off]) =
          *reinterpret_cast<const uint4*>(QKV + roff + colV + off);
    }
    __syncthreads();
#pragma unroll 4
    for (int s = 0; s < 128; ++s) {
      bf16x4 kk = *reinterpret_cast<const bf16x4*>(&Ks[s][d0]);
      bf16x4 vv = *reinterpret_cast<const bf16x4*>(&Vs[s][e0]);
      float kd[4], ve[4];
#pragma unroll
      for (int j = 0; j < 4; ++j) { kd[j] = (float)kk[j]; ve[j] = (float)vv[j]; }
#pragma unroll
      for (int i = 0; i < 4; ++i) {
        ks4[i] += kd[i];
#pragma unroll
        for (int j = 0; j < 4; ++j) acc[i][j] += kd[i] * ve[j];
      }
    }
    __syncthreads();
  }
#pragma unroll
  for (int i = 0; i < 4; ++i)
#pragma unroll
    for (int j = 0; j < 4; ++j)
      atomicAdd(&kvT[(size_t)bh * 4096 + (e0 + j) * 64 + (d0 + i)], acc[i][j]);
  if ((tid & 15) == 0) {
#pragma unroll
    for (int i = 0; i < 4; ++i)
      atomicAdd(&ksum[bh * 64 + d0 + i], ks4[i]);
  }
}

// ------------------------------------------------------------------ attn ----
// ATT[b,s, h*64+e] = (sum_d q[s,d]*kvT[e,d]) / (q[s,:].ksum + eps)   (bf16 out)
// MFMA: P^T[e,s] = kvT(A) @ q(Bt); D gives lane 4 consecutive e for fixed s ->
// zr-scale + b64 LDS write + coalesced global store. grid (32 s-tiles, 64 bh).
__global__ __launch_bounds__(256) void attn_kernel(const bf16* __restrict__ QKV,
                                                   const float* __restrict__ kvT,
                                                   const float* __restrict__ ksum,
                                                   bf16* __restrict__ ATT) {
  __shared__ bf16 qs[128][72];       // [s][d], pad 72 (16B-aligned, 2-way banks)
  __shared__ bf16 kvs[64][72];       // [e][d] bf16
  __shared__ bf16 Ps[128][72];       // [s][e] scaled result
  __shared__ float zr[128];
  __shared__ float kss[64];
  const int bh = blockIdx.y;
  const int b = bh >> 4, h = bh & 15;
  const int s0 = blockIdx.x * 128;
  const int tid = threadIdx.x, wave = tid >> 6, lane = tid & 63;
  const int quad = lane >> 4, l16 = lane & 15;
  const size_t base = (size_t)b * SEQ * 3072;
  const int colQ = h * 64;

#pragma unroll
  for (int i = 0; i < 4; ++i) {      // stage q tile 128x64 (b128 LDS writes)
    const int c = tid + i * 256;
    const int row = c >> 3, off = (c & 7) * 8;
    *reinterpret_cast<uint4*>(&qs[row][off]) =
        *reinterpret_cast<const uint4*>(QKV + base + (size_t)(s0 + row) * 3072 + colQ + off);
  }
  const float* kvg = kvT + (size_t)bh * 4096;
#pragma unroll
  for (int i = 0; i < 4; ++i) {      // stage kvT 64x64 fp32 -> bf16
    const int c = tid + i * 256;
    const int row = c >> 4, off = (c & 15) * 4;
    float4 f = *reinterpret_cast<const float4*>(kvg + row * 64 + off);
    bf16x4 o;
    o[0] = (bf16)f.x; o[1] = (bf16)f.y; o[2] = (bf16)f.z; o[3] = (bf16)f.w;
    *reinterpret_cast<bf16x4*>(&kvs[row][off]) = o;
  }
  if (tid < 64) kss[tid] = ksum[bh * 64 + tid];
  __syncthreads();

  if (tid < 128) {                   // zr = 1/(q.ksum + eps) per row
    float z = 0.f;
#pragma unroll
    for (int d = 0; d < 64; d += 4) {
      bf16x4 q4 = *reinterpret_cast<const bf16x4*>(&qs[tid][d]);
      z += (float)q4[0] * kss[d] + (float)q4[1] * kss[d + 1] +
           (float)q4[2] * kss[d + 2] + (float)q4[3] * kss[d + 3];
    }
    zr[tid] = 1.0f / (z + EPSV);
  }
  __syncthreads();

  // P^T = kvT @ q^T : M=e(64) -> mi 0..3 ; N=s(128) -> wave*32 + ni*16 ; K=d(64)
  const int wn = wave * 32;
  f32x4 pacc[4][2] = {};
#pragma unroll
  for (int ks = 0; ks < 2; ++ks) {
    s16x8 af[4], bf2[2];
#pragma unroll
    for (int mi = 0; mi < 4; ++mi)
      af[mi] = *reinterpret_cast<const s16x8*>(&kvs[mi * 16 + l16][ks * 32 + quad * 8]);
#pragma unroll
    for (int ni = 0; ni < 2; ++ni)
      bf2[ni] = *reinterpret_cast<const s16x8*>(&qs[wn + ni * 16 + l16][ks * 32 + quad * 8]);
#pragma unroll
    for (int mi = 0; mi < 4; ++mi)
#pragma unroll
      for (int ni = 0; ni < 2; ++ni)
        pacc[mi][ni] = __builtin_amdgcn_mfma_f32_16x16x32_bf16(af[mi], bf2[ni],
                                                               pacc[mi][ni], 0, 0, 0);
  }
  // D layout: col(s) = l16, row(e) = quad*4+reg -> lane has 4 consecutive e
#pragma unroll
  for (int ni = 0; ni < 2; ++ni) {
    const int s = wn + ni * 16 + l16;
    const float zi = zr[s];
#pragma unroll
    for (int mi = 0; mi < 4; ++mi) {
      bf16x4 o;
#pragma unroll
      for (int r = 0; r < 4; ++r) o[r] = (bf16)(pacc[mi][ni][r] * zi);
      *reinterpret_cast<bf16x4*>(&Ps[s][mi * 16 + quad * 4]) = o;
    }
  }
  __syncthreads();
#pragma unroll
  for (int i = 0; i < 4; ++i) {      // coalesced 16B stores
    const int c = tid + i * 256;
    const int row = c >> 3, ch = c & 7;
    *reinterpret_cast<uint4*>(ATT + ((size_t)b * SEQ + s0 + row) * DM + h * 64 + ch * 8) =
        *reinterpret_cast<const uint4*>(&Ps[row][ch * 8]);
  }
}

// ---------------------------------------------------------------- launch ----
extern "C" void kernel_launch(void* const* d_in, const int* in_sizes, int n_in,
                              void* d_out, int out_size, void* d_ws, size_t ws_size,
                              hipStream_t stream) {
  const float* x  = (const float*)d_in[0];
  const float* Wq = (const float*)d_in[1];
  const float* bq = (const float*)d_in[2];
  const float* Wk = (const float*)d_in[3];
  const float* bk = (const float*)d_in[4];
  const float* Wv = (const float*)d_in[5];
  const float* bv = (const float*)d_in[6];
  const float* Wo = (const float*)d_in[7];
  const float* bo = (const float*)d_in[8];
  float* out = (float*)d_out;

  char* ws = (char*)d_ws;
  bf16*  Xb   = (bf16*)ws;   ws += (size_t)MROWS * DM * 2;        // 32 MB
  bf16*  Wt   = (bf16*)ws;   ws += (size_t)4 * DM * DM * 2;       // 8 MB (qkv^T + o^T)
  bf16*  QKV  = (bf16*)ws;   ws += (size_t)MROWS * 3 * DM * 2;    // 96 MB
  bf16*  ATT  = (bf16*)ws;   ws += (size_t)MROWS * DM * 2;        // 32 MB
  float* kvT  = (float*)ws;  ws += (size_t)64 * 4096 * 4;         // 1 MB [bh][e][d]
  float* ksum = (float*)ws;  ws += (size_t)64 * 64 * 4;           // 16 KB

  (void)hipMemsetAsync(kvT, 0, (size_t)64 * 4096 * 4 + (size_t)64 * 64 * 4, stream);

  conv_x_kernel<<<MROWS * DM / 1024, 256, 0, stream>>>(x, Xb);
  conv_w_kernel<<<dim3(16, 16, 4), 256, 0, stream>>>(Wq, Wk, Wv, Wo, Wt);
  gemm_bf16<0><<<dim3(24, 128), 256, 0, stream>>>(Xb, Wt, QKV, 3 * DM, bq, bk, bv);
  kv_ksum_kernel<<<dim3(8, 64), 256, 0, stream>>>(QKV, kvT, ksum);
  attn_kernel<<<dim3(32, 64), 256, 0, stream>>>(QKV, kvT, ksum, ATT);
  gemm_bf16<1><<<dim3(8, 128), 256, 0, stream>>>(ATT, Wt + (size_t)3 * DM * DM, out, DM, bo, bo, bo);
}